// Round 10
// baseline (373.480 us; speedup 1.0000x reference)
//
#include <hip/hip_runtime.h>
#include <hip/hip_fp16.h>

#define N_NODES 100000
#define N_EDGES 50000
#define NNZ     3200000
#define D       32
#define NB      782                 // buckets of 128 nodes: ceil(100000/128)
#define BSH     7                   // bucket shift
#define BMSK    127u                // local-node mask
#define P1_CHUNK 4096
#define P1_T     1024
#define P1_BLKS  ((NNZ + P1_CHUNK - 1) / P1_CHUNK)   // 782
#define P2_T     512
#define P2_CAP  4608                // bucket capacity: mean 4096, sd ~64 (8 sigma)

// ---------------------------------------------------------------------------
// kXh: X (f32) -> Xh (f16 pairs packed in u32) — halves gather traffic in k2
// ---------------------------------------------------------------------------
__global__ void kXh(const float* __restrict__ X, unsigned int* __restrict__ XhU) {
    int i = blockIdx.x * blockDim.x + threadIdx.x;
    if (i >= N_NODES * (D / 2)) return;
    float2 v = ((const float2*)X)[i];
    __half2 h = __floats2half2_rn(v.x, v.y);
    XhU[i] = *(const unsigned int*)&h;
}

// ---------------------------------------------------------------------------
// K0: fuse weights.  M1 = W1 @ W2b, c1 = b1 @ W2b, A2 = W2a @ W, c2 = b2 @ W
// ---------------------------------------------------------------------------
__global__ void k0_weights(const float* __restrict__ W1, const float* __restrict__ b1,
                           const float* __restrict__ W2, const float* __restrict__ b2,
                           const float* __restrict__ Ww,
                           float* __restrict__ M1, float* __restrict__ c1,
                           float* __restrict__ A2, float* __restrict__ c2) {
    int t = threadIdx.x;            // 1024 threads
    int k = t >> 5, dd = t & 31;
    float m = 0.f, a = 0.f;
#pragma unroll
    for (int j = 0; j < D; ++j) {
        m = fmaf(W1[k * D + j], W2[(D + j) * D + dd], m);   // W1 @ W2b
        a = fmaf(W2[k * D + j], Ww[j * D + dd], a);          // W2a @ W
    }
    M1[k * D + dd] = m;
    A2[k * D + dd] = a;
    if (k == 0) {
        float cc1 = 0.f, cc2 = 0.f;
#pragma unroll
        for (int j = 0; j < D; ++j) {
            cc1 = fmaf(b1[j], W2[(D + j) * D + dd], cc1);
            cc2 = fmaf(b2[j], Ww[j * D + dd], cc2);
        }
        c1[dd] = cc1;
        c2[dd] = cc2;
    }
}

// ---------------------------------------------------------------------------
// k_seg: seg[e] = lower_bound(edges, e), one thread per e (0..N_EDGES incl.)
// ---------------------------------------------------------------------------
__global__ void k_seg(const int* __restrict__ edges, int* __restrict__ seg) {
    int e = blockIdx.x * blockDim.x + threadIdx.x;
    if (e > N_EDGES) return;
    int lo = 0, hi = NNZ;
    while (lo < hi) { int mid = (lo + hi) >> 1; if (edges[mid] < e) lo = mid + 1; else hi = mid; }
    seg[e] = lo;
}

// ---------------------------------------------------------------------------
// p1h: global bucket histogram (LDS-staged)
// ---------------------------------------------------------------------------
__global__ void p1h(const int* __restrict__ vertex, unsigned int* __restrict__ bcnt) {
    __shared__ unsigned int h[NB];
    for (int i = threadIdx.x; i < NB; i += blockDim.x) h[i] = 0;
    __syncthreads();
    int i = blockIdx.x * blockDim.x + threadIdx.x;
    int stride = gridDim.x * blockDim.x;
    for (; i < NNZ; i += stride) atomicAdd(&h[((unsigned)vertex[i]) >> BSH], 1u);
    __syncthreads();
    for (int j = threadIdx.x; j < NB; j += blockDim.x)
        if (h[j]) atomicAdd(&bcnt[j], h[j]);
}

// ---------------------------------------------------------------------------
// kscan: exclusive scan of the 782 bucket counts -> boff, bcur (1024 threads)
// ---------------------------------------------------------------------------
__global__ void kscan(const unsigned int* __restrict__ bcnt,
                      unsigned int* __restrict__ boff, unsigned int* __restrict__ bcur) {
    __shared__ unsigned int s[1024];
    int t = threadIdx.x;
    unsigned int v = (t < NB) ? bcnt[t] : 0;
    s[t] = v;
    __syncthreads();
    for (int off = 1; off < 1024; off <<= 1) {
        unsigned int u = (t >= off) ? s[t - off] : 0;
        __syncthreads();
        s[t] += u;
        __syncthreads();
    }
    if (t < NB) { unsigned int ex = s[t] - v; boff[t] = ex; bcur[t] = ex; }
    if (t == 0) boff[NB] = (unsigned)NNZ;
}

// ---------------------------------------------------------------------------
// p1: block-level radix partition (race-free). Each block orders its 4096
// incidences by bucket in LDS, reserves global space with ONE atomic per
// bucket, then writes coalesced runs. plist entry = (e<<7) | (v & 127).
// ---------------------------------------------------------------------------
__global__ __launch_bounds__(P1_T) void p1(const int* __restrict__ vertex,
                                           const int* __restrict__ edges,
                                           unsigned int* __restrict__ bcur,
                                           unsigned int* __restrict__ plist) {
    __shared__ unsigned int cnt[NB], excl[NB], cursor[NB], gbase[NB];
    __shared__ unsigned int scanb[P1_T];
    __shared__ unsigned int obuf[P1_CHUNK];
    __shared__ unsigned short obb[P1_CHUNK];
    int t = threadIdx.x;
    int c0 = blockIdx.x * P1_CHUNK;
    int cend = min(c0 + P1_CHUNK, NNZ);

    for (int i = t; i < NB; i += P1_T) cnt[i] = 0;
    __syncthreads();
    for (int i = c0 + t; i < cend; i += P1_T)
        atomicAdd(&cnt[((unsigned)vertex[i]) >> BSH], 1u);
    __syncthreads();

    unsigned int myc = (t < NB) ? cnt[t] : 0;
    scanb[t] = myc;
    __syncthreads();
    for (int off = 1; off < P1_T; off <<= 1) {
        unsigned int u = (t >= off) ? scanb[t - off] : 0;
        __syncthreads();
        scanb[t] += u;
        __syncthreads();
    }
    if (t < NB) {
        unsigned int ex = scanb[t] - myc;
        excl[t] = ex; cursor[t] = ex;
        gbase[t] = myc ? atomicAdd(&bcur[t], myc) : 0u;
    }
    __syncthreads();

    for (int i = c0 + t; i < cend; i += P1_T) {
        unsigned int v = (unsigned)vertex[i];
        unsigned int e = (unsigned)edges[i];
        unsigned int b = v >> BSH;
        unsigned int p = atomicAdd(&cursor[b], 1u);
        obuf[p] = (e << BSH) | (v & BMSK);
        obb[p]  = (unsigned short)b;
    }
    __syncthreads();

    int csize = cend - c0;
    for (int j = t; j < csize; j += P1_T) {
        unsigned int b = obb[j];
        plist[gbase[b] + (j - excl[b])] = obuf[j];
    }
}

// ---------------------------------------------------------------------------
// K2 (R4-validated): per-edge, one wave per edge.
//   Xe = sum_i a_i * Xh[v_i]   (f16 gather, 4x unrolled, 2 half-waves)
//   fe = Xe @ M1 + (sum a_i) * c1
//   write Fe[e] dense as packed f16 pairs (coalesced, no atomics)
// ---------------------------------------------------------------------------
__global__ void k2_edge(const unsigned int* __restrict__ XhU,
                        const float* __restrict__ atts,
                        const int* __restrict__ vertex,
                        const int* __restrict__ seg,
                        const float* __restrict__ M1,
                        const float* __restrict__ c1,
                        unsigned int* __restrict__ FeU) {
    __shared__ float Ms[D * D];
    __shared__ float cs[D];
    for (int i = threadIdx.x; i < D * D; i += blockDim.x) Ms[i] = M1[i];
    if (threadIdx.x < D) cs[threadIdx.x] = c1[threadIdx.x];
    __syncthreads();

    int wave = threadIdx.x >> 6;
    int lane = threadIdx.x & 63;
    int d    = lane & 31;
    int h    = lane >> 5;
    int e    = blockIdx.x * (blockDim.x >> 6) + wave;
    if (e >= N_EDGES) return;

    int start = seg[e];
    int end   = seg[e + 1];
    int hi16  = d >> 1, sel = d & 1;

    float acc0 = 0.f, acc1 = 0.f, acc2 = 0.f, acc3 = 0.f, sa = 0.f;
    int i = start + h;
    for (; i + 6 < end; i += 8) {
        int   v0 = vertex[i],     v1 = vertex[i + 2], v2 = vertex[i + 4], v3 = vertex[i + 6];
        float a0 = atts[i],       a1 = atts[i + 2],   a2 = atts[i + 4],   a3 = atts[i + 6];
        unsigned int w0 = XhU[v0 * 16 + hi16], w1 = XhU[v1 * 16 + hi16];
        unsigned int w2 = XhU[v2 * 16 + hi16], w3 = XhU[v3 * 16 + hi16];
        acc0 = fmaf(a0, __half2float(((const __half*)&w0)[sel]), acc0);
        acc1 = fmaf(a1, __half2float(((const __half*)&w1)[sel]), acc1);
        acc2 = fmaf(a2, __half2float(((const __half*)&w2)[sel]), acc2);
        acc3 = fmaf(a3, __half2float(((const __half*)&w3)[sel]), acc3);
        sa += (a0 + a1) + (a2 + a3);
    }
    for (; i < end; i += 2) {
        int v = vertex[i];
        float a = atts[i];
        unsigned int w = XhU[v * 16 + hi16];
        acc0 = fmaf(a, __half2float(((const __half*)&w)[sel]), acc0);
        sa += a;
    }
    float acc = (acc0 + acc1) + (acc2 + acc3);
    acc += __shfl(acc, lane ^ 32, 64);
    sa  += __shfl(sa,  lane ^ 32, 64);

    float fe = sa * cs[d];
#pragma unroll
    for (int k = 0; k < D; ++k) {
        float xk = __shfl(acc, k, 32);
        fe = fmaf(xk, Ms[k * D + d], fe);
    }

    float other = __shfl(fe, lane ^ 1, 64);
    float flo = sel ? other : fe;
    float fhi = sel ? fe : other;
    __half2 hv = __floats2half2_rn(flo, fhi);
    if (h == 0 && sel == 0) FeU[e * 16 + hi16] = *reinterpret_cast<unsigned int*>(&hv);
}

// ---------------------------------------------------------------------------
// p2: one 512-thread block per 128-node bucket. ZERO f32 atomics.
//   1) int histogram of local node (ent & 127)
//   2) Hillis-Steele scan (128) -> offsets
//   3) int-cursor scatter: sbuf sorted by node
//   4) NEW: per node, stage 32 sbuf entries cooperatively (one vector ds_read
//      per 32 entries instead of 32 uniform ds_reads) + __shfl broadcast;
//      FeU row gathers via agent-scope atomic loads (global_load sc0 ->
//      bypasses L1 miss-tracking, targets the suspected per-CU MSHR wall).
//   5) fused per-node epilogue: out = 0.5*(deg*(X@A2+c2) + (sf+X0)@W) + b
// ---------------------------------------------------------------------------
__global__ __launch_bounds__(P2_T) void p2(const unsigned int* __restrict__ plist,
                                           const unsigned int* __restrict__ FeU,
                                           const unsigned int* __restrict__ boff,
                                           const float* __restrict__ X,
                                           const float* __restrict__ X0,
                                           const float* __restrict__ A2,
                                           const float* __restrict__ c2,
                                           const float* __restrict__ Ww,
                                           const float* __restrict__ bw,
                                           float* __restrict__ out) {
    __shared__ unsigned int sbuf[P2_CAP];      // 18,432 B (node-sorted entries)
    __shared__ unsigned int cnt[128];
    __shared__ unsigned int pos[128];
    __shared__ unsigned int cursor[128];
    __shared__ float As[D * D], Ws[D * D], c2s[D], bws[D];
    int t = threadIdx.x;
    for (int i = t; i < D * D; i += P2_T) { As[i] = A2[i]; Ws[i] = Ww[i]; }
    if (t < D) { c2s[t] = c2[t]; bws[t] = bw[t]; }
    if (t < 128) cnt[t] = 0;
    __syncthreads();

    int b = blockIdx.x;
    int base = b << BSH;
    int start = (int)boff[b];
    int n = (int)boff[b + 1] - start;

    // 1) histogram by local node id
    for (int i = t; i < n; i += P2_T)
        atomicAdd(&cnt[plist[start + i] & BMSK], 1u);
    __syncthreads();

    // 2) inclusive scan of cnt into pos (Hillis-Steele over 128)
    unsigned int v = (t < 128) ? cnt[t] : 0;
    if (t < 128) pos[t] = v;
    __syncthreads();
    for (int off = 1; off < 128; off <<= 1) {
        unsigned int u = 0;
        if (t < 128 && t >= off) u = pos[t - off];
        __syncthreads();
        if (t < 128) pos[t] += u;
        __syncthreads();
    }
    if (t < 128) cursor[t] = pos[t] - v;       // exclusive offset
    __syncthreads();

    // 3) scatter into sbuf sorted by node
    for (int i = t; i < n; i += P2_T) {
        unsigned int ent = plist[start + i];
        unsigned int p = atomicAdd(&cursor[ent & BMSK], 1u);
        sbuf[p] = ent;
    }
    __syncthreads();

    // 4+5) 16 half-waves x 8 nodes; cooperative-staged gather + epilogue
    int hw = t >> 5, lane = t & 31;
    int hi16 = lane >> 1, sel = lane & 1;
    for (int r = 0; r < 8; ++r) {
        int ln = r * 16 + hw;
        int node = base + ln;
        if (node >= N_NODES) continue;
        int deg = (int)cnt[ln];
        int st  = (int)pos[ln] - deg;

        float sf0 = 0.f, sf1 = 0.f, sf2 = 0.f, sf3 = 0.f;
        for (int j0 = 0; j0 < deg; j0 += 32) {
            int ii = j0 + lane;
            unsigned int ent = (ii < deg) ? sbuf[st + ii] : 0u;   // 1 vector ds_read / 32 entries
            int m = min(32, deg - j0);
            int k = 0;
            for (; k + 3 < m; k += 4) {
                unsigned int e0 = __shfl(ent, k,     32) >> BSH;
                unsigned int e1 = __shfl(ent, k + 1, 32) >> BSH;
                unsigned int e2 = __shfl(ent, k + 2, 32) >> BSH;
                unsigned int e3 = __shfl(ent, k + 3, 32) >> BSH;
                unsigned int w0 = __hip_atomic_load((const unsigned int*)&FeU[e0 * 16 + hi16],
                                                    __ATOMIC_RELAXED, __HIP_MEMORY_SCOPE_AGENT);
                unsigned int w1 = __hip_atomic_load((const unsigned int*)&FeU[e1 * 16 + hi16],
                                                    __ATOMIC_RELAXED, __HIP_MEMORY_SCOPE_AGENT);
                unsigned int w2 = __hip_atomic_load((const unsigned int*)&FeU[e2 * 16 + hi16],
                                                    __ATOMIC_RELAXED, __HIP_MEMORY_SCOPE_AGENT);
                unsigned int w3 = __hip_atomic_load((const unsigned int*)&FeU[e3 * 16 + hi16],
                                                    __ATOMIC_RELAXED, __HIP_MEMORY_SCOPE_AGENT);
                sf0 += __half2float(((const __half*)&w0)[sel]);
                sf1 += __half2float(((const __half*)&w1)[sel]);
                sf2 += __half2float(((const __half*)&w2)[sel]);
                sf3 += __half2float(((const __half*)&w3)[sel]);
            }
            for (; k < m; ++k) {
                unsigned int e0 = __shfl(ent, k, 32) >> BSH;
                unsigned int w0 = __hip_atomic_load((const unsigned int*)&FeU[e0 * 16 + hi16],
                                                    __ATOMIC_RELAXED, __HIP_MEMORY_SCOPE_AGENT);
                sf0 += __half2float(((const __half*)&w0)[sel]);
            }
        }
        float sf = (sf0 + sf1) + (sf2 + sf3);

        float x = X[node * D + lane];
        float s1 = c2s[lane];
#pragma unroll
        for (int kk = 0; kk < D; ++kk) s1 = fmaf(__shfl(x, kk, 32), As[kk * D + lane], s1);
        float tt = sf + X0[node * D + lane];
        float s2 = 0.f;
#pragma unroll
        for (int kk = 0; kk < D; ++kk) s2 = fmaf(__shfl(tt, kk, 32), Ws[kk * D + lane], s2);
        out[node * D + lane] = 0.5f * fmaf((float)deg, s1, s2) + bws[lane];
    }
}

// ---------------------------------------------------------------------------
extern "C" void kernel_launch(void* const* d_in, const int* in_sizes, int n_in,
                              void* d_out, int out_size, void* d_ws, size_t ws_size,
                              hipStream_t stream) {
    const float* X      = (const float*)d_in[0];
    const float* X0     = (const float*)d_in[1];
    const float* atts   = (const float*)d_in[2];
    const float* W1w    = (const float*)d_in[3];
    const float* W1b    = (const float*)d_in[4];
    const float* W2w    = (const float*)d_in[5];
    const float* W2b    = (const float*)d_in[6];
    const float* Ww     = (const float*)d_in[7];
    const float* Wb     = (const float*)d_in[8];
    const int*   vertex = (const int*)d_in[9];
    const int*   edges  = (const int*)d_in[10];
    float*       out    = (float*)d_out;

    char* ws = (char*)d_ws;
    unsigned int* FeU   = (unsigned int*)(ws);                 //  3,200,000 B
    unsigned int* plist = (unsigned int*)(ws + 3200000);       // 12,800,000 B
    unsigned int* XhU   = (unsigned int*)(ws + 16000000);      //  6,400,000 B
    int*          seg   = (int*)         (ws + 22400000);      //    200,004 B
    unsigned int* bcnt  = (unsigned int*)(ws + 22600256);      //      3,128 B
    unsigned int* boff  = (unsigned int*)(ws + 22604352);      //      3,132 B
    unsigned int* bcur  = (unsigned int*)(ws + 22608512);      //      3,128 B
    float*        M1    = (float*)       (ws + 22612992);      //      4,096 B
    float*        A2    = (float*)       (ws + 22617088);      //      4,096 B
    float*        c1    = (float*)       (ws + 22621184);      //        128 B
    float*        c2    = (float*)       (ws + 22621312);      //        128 B

    hipMemsetAsync(bcnt, 0, NB * sizeof(unsigned int), stream);

    kXh       <<<(N_NODES * 16 + 255) / 256, 256, 0, stream>>>(X, XhU);
    k0_weights<<<1, 1024, 0, stream>>>(W1w, W1b, W2w, W2b, Ww, M1, c1, A2, c2);
    k_seg     <<<(N_EDGES + 256) / 256, 256, 0, stream>>>(edges, seg);
    p1h       <<<1024, 256, 0, stream>>>(vertex, bcnt);
    kscan     <<<1, 1024, 0, stream>>>(bcnt, boff, bcur);
    p1        <<<P1_BLKS, P1_T, 0, stream>>>(vertex, edges, bcur, plist);
    k2_edge   <<<(N_EDGES + 3) / 4, 256, 0, stream>>>(XhU, atts, vertex, seg, M1, c1, FeU);
    p2        <<<NB, P2_T, 0, stream>>>(plist, FeU, boff, X, X0, A2, c2, Ww, Wb, out);
}

// Round 11
// 272.797 us; speedup vs baseline: 1.3691x; 1.3691x over previous
//
#include <hip/hip_runtime.h>
#include <hip/hip_fp16.h>

#define N_NODES 100000
#define N_EDGES 50000
#define NNZ     3200000
#define D       32
#define NB      782                 // buckets of 128 nodes: ceil(100000/128)
#define BSH     7                   // bucket shift
#define BMSK    127u                // local-node mask
#define P1_CHUNK 4096
#define P1_T     1024
#define P1_BLKS  ((NNZ + P1_CHUNK - 1) / P1_CHUNK)   // 782
#define P2_T     512
#define P2_CAP  4608                // bucket capacity: mean 4096, sd ~64 (8 sigma)

__device__ __forceinline__ unsigned int pkadd(unsigned int a, unsigned int b) {
    __half2 r = __hadd2(*(__half2*)&a, *(__half2*)&b);   // v_pk_add_f16
    return *(unsigned int*)&r;
}

// ---------------------------------------------------------------------------
// kXh: X (f32) -> Xh (f16 pairs packed in u32) — halves gather traffic in k2
// ---------------------------------------------------------------------------
__global__ void kXh(const float* __restrict__ X, unsigned int* __restrict__ XhU) {
    int i = blockIdx.x * blockDim.x + threadIdx.x;
    if (i >= N_NODES * (D / 2)) return;
    float2 v = ((const float2*)X)[i];
    __half2 h = __floats2half2_rn(v.x, v.y);
    XhU[i] = *(const unsigned int*)&h;
}

// ---------------------------------------------------------------------------
// K0: fuse weights.  M1 = W1 @ W2b, c1 = b1 @ W2b, A2 = W2a @ W, c2 = b2 @ W
// ---------------------------------------------------------------------------
__global__ void k0_weights(const float* __restrict__ W1, const float* __restrict__ b1,
                           const float* __restrict__ W2, const float* __restrict__ b2,
                           const float* __restrict__ Ww,
                           float* __restrict__ M1, float* __restrict__ c1,
                           float* __restrict__ A2, float* __restrict__ c2) {
    int t = threadIdx.x;            // 1024 threads
    int k = t >> 5, dd = t & 31;
    float m = 0.f, a = 0.f;
#pragma unroll
    for (int j = 0; j < D; ++j) {
        m = fmaf(W1[k * D + j], W2[(D + j) * D + dd], m);   // W1 @ W2b
        a = fmaf(W2[k * D + j], Ww[j * D + dd], a);          // W2a @ W
    }
    M1[k * D + dd] = m;
    A2[k * D + dd] = a;
    if (k == 0) {
        float cc1 = 0.f, cc2 = 0.f;
#pragma unroll
        for (int j = 0; j < D; ++j) {
            cc1 = fmaf(b1[j], W2[(D + j) * D + dd], cc1);
            cc2 = fmaf(b2[j], Ww[j * D + dd], cc2);
        }
        c1[dd] = cc1;
        c2[dd] = cc2;
    }
}

// ---------------------------------------------------------------------------
// k_seg: seg[e] = lower_bound(edges, e), one thread per e (0..N_EDGES incl.)
// ---------------------------------------------------------------------------
__global__ void k_seg(const int* __restrict__ edges, int* __restrict__ seg) {
    int e = blockIdx.x * blockDim.x + threadIdx.x;
    if (e > N_EDGES) return;
    int lo = 0, hi = NNZ;
    while (lo < hi) { int mid = (lo + hi) >> 1; if (edges[mid] < e) lo = mid + 1; else hi = mid; }
    seg[e] = lo;
}

// ---------------------------------------------------------------------------
// p1h: global bucket histogram (LDS-staged)
// ---------------------------------------------------------------------------
__global__ void p1h(const int* __restrict__ vertex, unsigned int* __restrict__ bcnt) {
    __shared__ unsigned int h[NB];
    for (int i = threadIdx.x; i < NB; i += blockDim.x) h[i] = 0;
    __syncthreads();
    int i = blockIdx.x * blockDim.x + threadIdx.x;
    int stride = gridDim.x * blockDim.x;
    for (; i < NNZ; i += stride) atomicAdd(&h[((unsigned)vertex[i]) >> BSH], 1u);
    __syncthreads();
    for (int j = threadIdx.x; j < NB; j += blockDim.x)
        if (h[j]) atomicAdd(&bcnt[j], h[j]);
}

// ---------------------------------------------------------------------------
// kscan: exclusive scan of the 782 bucket counts -> boff, bcur (1024 threads)
// ---------------------------------------------------------------------------
__global__ void kscan(const unsigned int* __restrict__ bcnt,
                      unsigned int* __restrict__ boff, unsigned int* __restrict__ bcur) {
    __shared__ unsigned int s[1024];
    int t = threadIdx.x;
    unsigned int v = (t < NB) ? bcnt[t] : 0;
    s[t] = v;
    __syncthreads();
    for (int off = 1; off < 1024; off <<= 1) {
        unsigned int u = (t >= off) ? s[t - off] : 0;
        __syncthreads();
        s[t] += u;
        __syncthreads();
    }
    if (t < NB) { unsigned int ex = s[t] - v; boff[t] = ex; bcur[t] = ex; }
    if (t == 0) boff[NB] = (unsigned)NNZ;
}

// ---------------------------------------------------------------------------
// p1: block-level radix partition (race-free). Each block orders its 4096
// incidences by bucket in LDS, reserves global space with ONE atomic per
// bucket, then writes coalesced runs. plist entry = (e<<7) | (v & 127).
// ---------------------------------------------------------------------------
__global__ __launch_bounds__(P1_T) void p1(const int* __restrict__ vertex,
                                           const int* __restrict__ edges,
                                           unsigned int* __restrict__ bcur,
                                           unsigned int* __restrict__ plist) {
    __shared__ unsigned int cnt[NB], excl[NB], cursor[NB], gbase[NB];
    __shared__ unsigned int scanb[P1_T];
    __shared__ unsigned int obuf[P1_CHUNK];
    __shared__ unsigned short obb[P1_CHUNK];
    int t = threadIdx.x;
    int c0 = blockIdx.x * P1_CHUNK;
    int cend = min(c0 + P1_CHUNK, NNZ);

    for (int i = t; i < NB; i += P1_T) cnt[i] = 0;
    __syncthreads();
    for (int i = c0 + t; i < cend; i += P1_T)
        atomicAdd(&cnt[((unsigned)vertex[i]) >> BSH], 1u);
    __syncthreads();

    unsigned int myc = (t < NB) ? cnt[t] : 0;
    scanb[t] = myc;
    __syncthreads();
    for (int off = 1; off < P1_T; off <<= 1) {
        unsigned int u = (t >= off) ? scanb[t - off] : 0;
        __syncthreads();
        scanb[t] += u;
        __syncthreads();
    }
    if (t < NB) {
        unsigned int ex = scanb[t] - myc;
        excl[t] = ex; cursor[t] = ex;
        gbase[t] = myc ? atomicAdd(&bcur[t], myc) : 0u;
    }
    __syncthreads();

    for (int i = c0 + t; i < cend; i += P1_T) {
        unsigned int v = (unsigned)vertex[i];
        unsigned int e = (unsigned)edges[i];
        unsigned int b = v >> BSH;
        unsigned int p = atomicAdd(&cursor[b], 1u);
        obuf[p] = (e << BSH) | (v & BMSK);
        obb[p]  = (unsigned short)b;
    }
    __syncthreads();

    int csize = cend - c0;
    for (int j = t; j < csize; j += P1_T) {
        unsigned int b = obb[j];
        plist[gbase[b] + (j - excl[b])] = obuf[j];
    }
}

// ---------------------------------------------------------------------------
// K2 (R4-validated): per-edge, one wave per edge.
//   Xe = sum_i a_i * Xh[v_i]   (f16 gather, 4x unrolled, 2 half-waves)
//   fe = Xe @ M1 + (sum a_i) * c1
//   write Fe[e] dense as packed f16 pairs (coalesced, no atomics)
// ---------------------------------------------------------------------------
__global__ void k2_edge(const unsigned int* __restrict__ XhU,
                        const float* __restrict__ atts,
                        const int* __restrict__ vertex,
                        const int* __restrict__ seg,
                        const float* __restrict__ M1,
                        const float* __restrict__ c1,
                        unsigned int* __restrict__ FeU) {
    __shared__ float Ms[D * D];
    __shared__ float cs[D];
    for (int i = threadIdx.x; i < D * D; i += blockDim.x) Ms[i] = M1[i];
    if (threadIdx.x < D) cs[threadIdx.x] = c1[threadIdx.x];
    __syncthreads();

    int wave = threadIdx.x >> 6;
    int lane = threadIdx.x & 63;
    int d    = lane & 31;
    int h    = lane >> 5;
    int e    = blockIdx.x * (blockDim.x >> 6) + wave;
    if (e >= N_EDGES) return;

    int start = seg[e];
    int end   = seg[e + 1];
    int hi16  = d >> 1, sel = d & 1;

    float acc0 = 0.f, acc1 = 0.f, acc2 = 0.f, acc3 = 0.f, sa = 0.f;
    int i = start + h;
    for (; i + 6 < end; i += 8) {
        int   v0 = vertex[i],     v1 = vertex[i + 2], v2 = vertex[i + 4], v3 = vertex[i + 6];
        float a0 = atts[i],       a1 = atts[i + 2],   a2 = atts[i + 4],   a3 = atts[i + 6];
        unsigned int w0 = XhU[v0 * 16 + hi16], w1 = XhU[v1 * 16 + hi16];
        unsigned int w2 = XhU[v2 * 16 + hi16], w3 = XhU[v3 * 16 + hi16];
        acc0 = fmaf(a0, __half2float(((const __half*)&w0)[sel]), acc0);
        acc1 = fmaf(a1, __half2float(((const __half*)&w1)[sel]), acc1);
        acc2 = fmaf(a2, __half2float(((const __half*)&w2)[sel]), acc2);
        acc3 = fmaf(a3, __half2float(((const __half*)&w3)[sel]), acc3);
        sa += (a0 + a1) + (a2 + a3);
    }
    for (; i < end; i += 2) {
        int v = vertex[i];
        float a = atts[i];
        unsigned int w = XhU[v * 16 + hi16];
        acc0 = fmaf(a, __half2float(((const __half*)&w)[sel]), acc0);
        sa += a;
    }
    float acc = (acc0 + acc1) + (acc2 + acc3);
    acc += __shfl(acc, lane ^ 32, 64);
    sa  += __shfl(sa,  lane ^ 32, 64);

    float fe = sa * cs[d];
#pragma unroll
    for (int k = 0; k < D; ++k) {
        float xk = __shfl(acc, k, 32);
        fe = fmaf(xk, Ms[k * D + d], fe);
    }

    float other = __shfl(fe, lane ^ 1, 64);
    float flo = sel ? other : fe;
    float fhi = sel ? fe : other;
    __half2 hv = __floats2half2_rn(flo, fhi);
    if (h == 0 && sel == 0) FeU[e * 16 + hi16] = *reinterpret_cast<unsigned int*>(&hv);
}

// ---------------------------------------------------------------------------
// p2: one 512-thread block per 128-node bucket. Sort phases 1-3 = R9
// (validated). Phase 4 NEW: lane=(row-slot k8, 16B-chunk h4); one
// global_load_dwordx4 per lane fetches 8 Fe rows per instruction (512B);
// packed-f16 accumulate (v_pk_add_f16); xor-reduce over row-slots; shfl
// redistribution to lane=d layout. Unroll-2 (two acc sets) for 16 rows in
// flight per half-wave. Zero f32 atomics, zero extra LDS traffic.
// ---------------------------------------------------------------------------
__global__ __launch_bounds__(P2_T) void p2(const unsigned int* __restrict__ plist,
                                           const unsigned int* __restrict__ FeU,
                                           const unsigned int* __restrict__ boff,
                                           const float* __restrict__ X,
                                           const float* __restrict__ X0,
                                           const float* __restrict__ A2,
                                           const float* __restrict__ c2,
                                           const float* __restrict__ Ww,
                                           const float* __restrict__ bw,
                                           float* __restrict__ out) {
    __shared__ unsigned int sbuf[P2_CAP];      // 18,432 B (node-sorted entries)
    __shared__ unsigned int cnt[128];
    __shared__ unsigned int pos[128];
    __shared__ unsigned int cursor[128];
    __shared__ float As[D * D], Ws[D * D], c2s[D], bws[D];
    int t = threadIdx.x;
    for (int i = t; i < D * D; i += P2_T) { As[i] = A2[i]; Ws[i] = Ww[i]; }
    if (t < D) { c2s[t] = c2[t]; bws[t] = bw[t]; }
    if (t < 128) cnt[t] = 0;
    __syncthreads();

    int b = blockIdx.x;
    int base = b << BSH;
    int start = (int)boff[b];
    int n = (int)boff[b + 1] - start;

    // 1) histogram by local node id
    for (int i = t; i < n; i += P2_T)
        atomicAdd(&cnt[plist[start + i] & BMSK], 1u);
    __syncthreads();

    // 2) inclusive scan of cnt into pos (Hillis-Steele over 128)
    unsigned int v = (t < 128) ? cnt[t] : 0;
    if (t < 128) pos[t] = v;
    __syncthreads();
    for (int off = 1; off < 128; off <<= 1) {
        unsigned int u = 0;
        if (t < 128 && t >= off) u = pos[t - off];
        __syncthreads();
        if (t < 128) pos[t] += u;
        __syncthreads();
    }
    if (t < 128) cursor[t] = pos[t] - v;       // exclusive offset
    __syncthreads();

    // 3) scatter into sbuf sorted by node
    for (int i = t; i < n; i += P2_T) {
        unsigned int ent = plist[start + i];
        unsigned int p = atomicAdd(&cursor[ent & BMSK], 1u);
        sbuf[p] = ent;
    }
    __syncthreads();

    // 4+5) 16 half-waves x 8 nodes; 8-rows-per-instruction gather + epilogue
    int hw = t >> 5, lane = t & 31;
    int k8 = lane >> 2;                        // row slot 0..7
    int h4 = lane & 3;                         // 16B chunk 0..3
    for (int r = 0; r < 8; ++r) {
        int ln = r * 16 + hw;
        int node = base + ln;
        if (node >= N_NODES) continue;
        int deg = (int)cnt[ln];
        int st  = (int)pos[ln] - deg;

        unsigned int a0 = 0u, a1 = 0u, a2 = 0u, a3 = 0u;   // 8 f16 accum (set A)
        unsigned int a4 = 0u, a5 = 0u, a6 = 0u, a7 = 0u;   // set B
        for (int j0 = 0; j0 < deg; j0 += 16) {
            int iA = j0 + k8, iB = j0 + 8 + k8;
            bool vA = (iA < deg), vB = (iB < deg);
            unsigned int eA = vA ? (sbuf[st + iA] >> BSH) : 0u;
            unsigned int eB = vB ? (sbuf[st + iB] >> BSH) : 0u;
            uint4 wA = *(const uint4*)(FeU + eA * 16 + h4 * 4);
            uint4 wB = *(const uint4*)(FeU + eB * 16 + h4 * 4);
            if (!vA) { wA.x = 0u; wA.y = 0u; wA.z = 0u; wA.w = 0u; }
            if (!vB) { wB.x = 0u; wB.y = 0u; wB.z = 0u; wB.w = 0u; }
            a0 = pkadd(a0, wA.x); a1 = pkadd(a1, wA.y);
            a2 = pkadd(a2, wA.z); a3 = pkadd(a3, wA.w);
            a4 = pkadd(a4, wB.x); a5 = pkadd(a5, wB.y);
            a6 = pkadd(a6, wB.z); a7 = pkadd(a7, wB.w);
        }
        a0 = pkadd(a0, a4); a1 = pkadd(a1, a5);
        a2 = pkadd(a2, a6); a3 = pkadd(a3, a7);
        // reduce across row-slots (lanes differing in bits 2..4, same h4)
#pragma unroll
        for (int m = 4; m < 32; m <<= 1) {
            a0 = pkadd(a0, __shfl_xor(a0, m, 32));
            a1 = pkadd(a1, __shfl_xor(a1, m, 32));
            a2 = pkadd(a2, __shfl_xor(a2, m, 32));
            a3 = pkadd(a3, __shfl_xor(a3, m, 32));
        }
        // redistribute: lane j needs sf[j]; group h=j>>3 holds d in [8h,8h+8)
        unsigned int b0 = __shfl(a0, lane >> 3, 32);
        unsigned int b1 = __shfl(a1, lane >> 3, 32);
        unsigned int b2 = __shfl(a2, lane >> 3, 32);
        unsigned int b3 = __shfl(a3, lane >> 3, 32);
        unsigned int x01 = (lane & 2) ? b1 : b0;
        unsigned int x23 = (lane & 2) ? b3 : b2;
        unsigned int xx  = (lane & 4) ? x23 : x01;
        __half2 hh = *(__half2*)&xx;
        float sf = (lane & 1) ? __high2float(hh) : __low2float(hh);

        float x = X[node * D + lane];
        float s1 = c2s[lane];
#pragma unroll
        for (int kk = 0; kk < D; ++kk) s1 = fmaf(__shfl(x, kk, 32), As[kk * D + lane], s1);
        float tt = sf + X0[node * D + lane];
        float s2 = 0.f;
#pragma unroll
        for (int kk = 0; kk < D; ++kk) s2 = fmaf(__shfl(tt, kk, 32), Ws[kk * D + lane], s2);
        out[node * D + lane] = 0.5f * fmaf((float)deg, s1, s2) + bws[lane];
    }
}

// ---------------------------------------------------------------------------
extern "C" void kernel_launch(void* const* d_in, const int* in_sizes, int n_in,
                              void* d_out, int out_size, void* d_ws, size_t ws_size,
                              hipStream_t stream) {
    const float* X      = (const float*)d_in[0];
    const float* X0     = (const float*)d_in[1];
    const float* atts   = (const float*)d_in[2];
    const float* W1w    = (const float*)d_in[3];
    const float* W1b    = (const float*)d_in[4];
    const float* W2w    = (const float*)d_in[5];
    const float* W2b    = (const float*)d_in[6];
    const float* Ww     = (const float*)d_in[7];
    const float* Wb     = (const float*)d_in[8];
    const int*   vertex = (const int*)d_in[9];
    const int*   edges  = (const int*)d_in[10];
    float*       out    = (float*)d_out;

    char* ws = (char*)d_ws;
    unsigned int* FeU   = (unsigned int*)(ws);                 //  3,200,000 B
    unsigned int* plist = (unsigned int*)(ws + 3200000);       // 12,800,000 B
    unsigned int* XhU   = (unsigned int*)(ws + 16000000);      //  6,400,000 B
    int*          seg   = (int*)         (ws + 22400000);      //    200,004 B
    unsigned int* bcnt  = (unsigned int*)(ws + 22600256);      //      3,128 B
    unsigned int* boff  = (unsigned int*)(ws + 22604352);      //      3,132 B
    unsigned int* bcur  = (unsigned int*)(ws + 22608512);      //      3,128 B
    float*        M1    = (float*)       (ws + 22612992);      //      4,096 B
    float*        A2    = (float*)       (ws + 22617088);      //      4,096 B
    float*        c1    = (float*)       (ws + 22621184);      //        128 B
    float*        c2    = (float*)       (ws + 22621312);      //        128 B

    hipMemsetAsync(bcnt, 0, NB * sizeof(unsigned int), stream);

    kXh       <<<(N_NODES * 16 + 255) / 256, 256, 0, stream>>>(X, XhU);
    k0_weights<<<1, 1024, 0, stream>>>(W1w, W1b, W2w, W2b, Ww, M1, c1, A2, c2);
    k_seg     <<<(N_EDGES + 256) / 256, 256, 0, stream>>>(edges, seg);
    p1h       <<<1024, 256, 0, stream>>>(vertex, bcnt);
    kscan     <<<1, 1024, 0, stream>>>(bcnt, boff, bcur);
    p1        <<<P1_BLKS, P1_T, 0, stream>>>(vertex, edges, bcur, plist);
    k2_edge   <<<(N_EDGES + 3) / 4, 256, 0, stream>>>(XhU, atts, vertex, seg, M1, c1, FeU);
    p2        <<<NB, P2_T, 0, stream>>>(plist, FeU, boff, X, X0, A2, c2, Ww, Wb, out);
}

// Round 12
// 229.410 us; speedup vs baseline: 1.6280x; 1.1891x over previous
//
#include <hip/hip_runtime.h>
#include <hip/hip_fp16.h>

#define N_NODES 100000
#define N_EDGES 50000
#define NNZ     3200000
#define D       32
#define NB      782                 // buckets of 128 nodes: ceil(100000/128)
#define BSH     7                   // bucket shift
#define BMSK    127u                // local-node mask
#define P1_CHUNK 4096
#define P1_T     1024
#define P1_BLKS  ((NNZ + P1_CHUNK - 1) / P1_CHUNK)   // 782
#define P2_T     512
#define P2_CAP  4608                // bucket capacity: mean 4096, sd ~64 (8 sigma)

__device__ __forceinline__ unsigned int pkadd(unsigned int a, unsigned int b) {
    __half2 r = __hadd2(*(__half2*)&a, *(__half2*)&b);   // v_pk_add_f16
    return *(unsigned int*)&r;
}

// ---------------------------------------------------------------------------
// kXh: X (f32) -> Xh (f16 pairs packed in u32) — halves gather traffic in k2
// ---------------------------------------------------------------------------
__global__ void kXh(const float* __restrict__ X, unsigned int* __restrict__ XhU) {
    int i = blockIdx.x * blockDim.x + threadIdx.x;
    if (i >= N_NODES * (D / 2)) return;
    float2 v = ((const float2*)X)[i];
    __half2 h = __floats2half2_rn(v.x, v.y);
    XhU[i] = *(const unsigned int*)&h;
}

// ---------------------------------------------------------------------------
// K0: fuse weights.  M1 = W1 @ W2b, c1 = b1 @ W2b, A2 = W2a @ W, c2 = b2 @ W
// ---------------------------------------------------------------------------
__global__ void k0_weights(const float* __restrict__ W1, const float* __restrict__ b1,
                           const float* __restrict__ W2, const float* __restrict__ b2,
                           const float* __restrict__ Ww,
                           float* __restrict__ M1, float* __restrict__ c1,
                           float* __restrict__ A2, float* __restrict__ c2) {
    int t = threadIdx.x;            // 1024 threads
    int k = t >> 5, dd = t & 31;
    float m = 0.f, a = 0.f;
#pragma unroll
    for (int j = 0; j < D; ++j) {
        m = fmaf(W1[k * D + j], W2[(D + j) * D + dd], m);   // W1 @ W2b
        a = fmaf(W2[k * D + j], Ww[j * D + dd], a);          // W2a @ W
    }
    M1[k * D + dd] = m;
    A2[k * D + dd] = a;
    if (k == 0) {
        float cc1 = 0.f, cc2 = 0.f;
#pragma unroll
        for (int j = 0; j < D; ++j) {
            cc1 = fmaf(b1[j], W2[(D + j) * D + dd], cc1);
            cc2 = fmaf(b2[j], Ww[j * D + dd], cc2);
        }
        c1[dd] = cc1;
        c2[dd] = cc2;
    }
}

// ---------------------------------------------------------------------------
// k_seg: seg[e] = lower_bound(edges, e), one thread per e (0..N_EDGES incl.)
// ---------------------------------------------------------------------------
__global__ void k_seg(const int* __restrict__ edges, int* __restrict__ seg) {
    int e = blockIdx.x * blockDim.x + threadIdx.x;
    if (e > N_EDGES) return;
    int lo = 0, hi = NNZ;
    while (lo < hi) { int mid = (lo + hi) >> 1; if (edges[mid] < e) lo = mid + 1; else hi = mid; }
    seg[e] = lo;
}

// ---------------------------------------------------------------------------
// p1h: global bucket histogram (LDS-staged)
// ---------------------------------------------------------------------------
__global__ void p1h(const int* __restrict__ vertex, unsigned int* __restrict__ bcnt) {
    __shared__ unsigned int h[NB];
    for (int i = threadIdx.x; i < NB; i += blockDim.x) h[i] = 0;
    __syncthreads();
    int i = blockIdx.x * blockDim.x + threadIdx.x;
    int stride = gridDim.x * blockDim.x;
    for (; i < NNZ; i += stride) atomicAdd(&h[((unsigned)vertex[i]) >> BSH], 1u);
    __syncthreads();
    for (int j = threadIdx.x; j < NB; j += blockDim.x)
        if (h[j]) atomicAdd(&bcnt[j], h[j]);
}

// ---------------------------------------------------------------------------
// kscan: exclusive scan of the 782 bucket counts -> boff, bcur (1024 threads)
// ---------------------------------------------------------------------------
__global__ void kscan(const unsigned int* __restrict__ bcnt,
                      unsigned int* __restrict__ boff, unsigned int* __restrict__ bcur) {
    __shared__ unsigned int s[1024];
    int t = threadIdx.x;
    unsigned int v = (t < NB) ? bcnt[t] : 0;
    s[t] = v;
    __syncthreads();
    for (int off = 1; off < 1024; off <<= 1) {
        unsigned int u = (t >= off) ? s[t - off] : 0;
        __syncthreads();
        s[t] += u;
        __syncthreads();
    }
    if (t < NB) { unsigned int ex = s[t] - v; boff[t] = ex; bcur[t] = ex; }
    if (t == 0) boff[NB] = (unsigned)NNZ;
}

// ---------------------------------------------------------------------------
// p1: block-level radix partition (race-free). Each block orders its 4096
// incidences by bucket in LDS, reserves global space with ONE atomic per
// bucket, then writes coalesced runs. plist entry = (e<<7) | (v & 127).
// ---------------------------------------------------------------------------
__global__ __launch_bounds__(P1_T) void p1(const int* __restrict__ vertex,
                                           const int* __restrict__ edges,
                                           unsigned int* __restrict__ bcur,
                                           unsigned int* __restrict__ plist) {
    __shared__ unsigned int cnt[NB], excl[NB], cursor[NB], gbase[NB];
    __shared__ unsigned int scanb[P1_T];
    __shared__ unsigned int obuf[P1_CHUNK];
    __shared__ unsigned short obb[P1_CHUNK];
    int t = threadIdx.x;
    int c0 = blockIdx.x * P1_CHUNK;
    int cend = min(c0 + P1_CHUNK, NNZ);

    for (int i = t; i < NB; i += P1_T) cnt[i] = 0;
    __syncthreads();
    for (int i = c0 + t; i < cend; i += P1_T)
        atomicAdd(&cnt[((unsigned)vertex[i]) >> BSH], 1u);
    __syncthreads();

    unsigned int myc = (t < NB) ? cnt[t] : 0;
    scanb[t] = myc;
    __syncthreads();
    for (int off = 1; off < P1_T; off <<= 1) {
        unsigned int u = (t >= off) ? scanb[t - off] : 0;
        __syncthreads();
        scanb[t] += u;
        __syncthreads();
    }
    if (t < NB) {
        unsigned int ex = scanb[t] - myc;
        excl[t] = ex; cursor[t] = ex;
        gbase[t] = myc ? atomicAdd(&bcur[t], myc) : 0u;
    }
    __syncthreads();

    for (int i = c0 + t; i < cend; i += P1_T) {
        unsigned int v = (unsigned)vertex[i];
        unsigned int e = (unsigned)edges[i];
        unsigned int b = v >> BSH;
        unsigned int p = atomicAdd(&cursor[b], 1u);
        obuf[p] = (e << BSH) | (v & BMSK);
        obb[p]  = (unsigned short)b;
    }
    __syncthreads();

    int csize = cend - c0;
    for (int j = t; j < csize; j += P1_T) {
        unsigned int b = obb[j];
        plist[gbase[b] + (j - excl[b])] = obuf[j];
    }
}

// ---------------------------------------------------------------------------
// K2: per-edge, one wave per edge. R12: 16-rows-per-instruction gather.
//   lane = (row-slot k16 = lane>>2, 16B chunk h4 = lane&3); one
//   global_load_dwordx4 fetches chunk h4 of 16 DIFFERENT Xh rows per wave
//   instruction (1 KB/instr vs 64 B before — the measured per-CU wall is
//   ~25 cy per gather INSTRUCTION, so rows/instr is the only lever).
//   vertex/atts staged 64-wide coalesced, broadcast via shfl. f32
//   accumulate (8 elems/lane), xor-reduce over slots, pack->f16,
//   4-shfl redistribution to lane=d; then the R4-validated M1 GEMV and
//   packed-f16 Fe write, unchanged.
// ---------------------------------------------------------------------------
__global__ void k2_edge(const unsigned int* __restrict__ XhU,
                        const float* __restrict__ atts,
                        const int* __restrict__ vertex,
                        const int* __restrict__ seg,
                        const float* __restrict__ M1,
                        const float* __restrict__ c1,
                        unsigned int* __restrict__ FeU) {
    __shared__ float Ms[D * D];
    __shared__ float cs[D];
    for (int i = threadIdx.x; i < D * D; i += blockDim.x) Ms[i] = M1[i];
    if (threadIdx.x < D) cs[threadIdx.x] = c1[threadIdx.x];
    __syncthreads();

    int wave = threadIdx.x >> 6;
    int lane = threadIdx.x & 63;
    int d    = lane & 31;
    int h    = lane >> 5;
    int e    = blockIdx.x * (blockDim.x >> 6) + wave;
    if (e >= N_EDGES) return;

    int start = seg[e];
    int len   = seg[e + 1] - start;
    int k16   = lane >> 2;             // row slot 0..15
    int h4    = lane & 3;              // 16B chunk 0..3

    float a0 = 0.f, a1 = 0.f, a2 = 0.f, a3 = 0.f;
    float a4 = 0.f, a5 = 0.f, a6 = 0.f, a7 = 0.f;
    float sa = 0.f;

    for (int base = 0; base < len; base += 64) {
        int off = base + lane;
        int vv = 0; float aa = 0.f;
        if (off < len) { vv = vertex[start + off]; aa = atts[start + off]; }
#pragma unroll
        for (int g = 0; g < 4; ++g) {
            int   vk = __shfl(vv, g * 16 + k16, 64);
            float ak = __shfl(aa, g * 16 + k16, 64);
            uint4 w = *(const uint4*)(XhU + vk * 16 + h4 * 4);
            __half2 h0 = *(__half2*)&w.x, h1 = *(__half2*)&w.y;
            __half2 h2 = *(__half2*)&w.z, h3 = *(__half2*)&w.w;
            a0 = fmaf(ak, __low2float(h0), a0); a1 = fmaf(ak, __high2float(h0), a1);
            a2 = fmaf(ak, __low2float(h1), a2); a3 = fmaf(ak, __high2float(h1), a3);
            a4 = fmaf(ak, __low2float(h2), a4); a5 = fmaf(ak, __high2float(h2), a5);
            a6 = fmaf(ak, __low2float(h3), a6); a7 = fmaf(ak, __high2float(h3), a7);
            sa += ak;
        }
    }

    // reduce across the 16 row slots (and halves): lanes differing in bits 2..5
#pragma unroll
    for (int m = 4; m < 64; m <<= 1) {
        a0 += __shfl_xor(a0, m, 64); a1 += __shfl_xor(a1, m, 64);
        a2 += __shfl_xor(a2, m, 64); a3 += __shfl_xor(a3, m, 64);
        a4 += __shfl_xor(a4, m, 64); a5 += __shfl_xor(a5, m, 64);
        a6 += __shfl_xor(a6, m, 64); a7 += __shfl_xor(a7, m, 64);
        sa += __shfl_xor(sa, m, 64);
    }

    // pack chunk (8 f32 -> 4 dwords of f16 pairs), redistribute to lane=d
    __half2 p0 = __floats2half2_rn(a0, a1), p1 = __floats2half2_rn(a2, a3);
    __half2 p2 = __floats2half2_rn(a4, a5), p3 = __floats2half2_rn(a6, a7);
    unsigned int u0 = *(unsigned int*)&p0, u1 = *(unsigned int*)&p1;
    unsigned int u2 = *(unsigned int*)&p2, u3 = *(unsigned int*)&p3;
    int src = d >> 3;                   // lane src (0..3) in this half holds chunk d>>3
    unsigned int b0 = __shfl(u0, src, 32), b1 = __shfl(u1, src, 32);
    unsigned int b2 = __shfl(u2, src, 32), b3 = __shfl(u3, src, 32);
    unsigned int x01 = (d & 2) ? b1 : b0;
    unsigned int x23 = (d & 2) ? b3 : b2;
    unsigned int xx  = (d & 4) ? x23 : x01;
    __half2 hh = *(__half2*)&xx;
    float acc = (d & 1) ? __high2float(hh) : __low2float(hh);   // Xe[d]

    // fe[d] = sum_k Xe[k] * M1[k][d] + sa * c1[d]
    float fe = sa * cs[d];
#pragma unroll
    for (int k = 0; k < D; ++k) {
        float xk = __shfl(acc, k, 32);
        fe = fmaf(xk, Ms[k * D + d], fe);
    }

    int hi16 = d >> 1, sel = d & 1;
    float other = __shfl(fe, lane ^ 1, 64);
    float flo = sel ? other : fe;
    float fhi = sel ? fe : other;
    __half2 hv = __floats2half2_rn(flo, fhi);
    if (h == 0 && sel == 0) FeU[e * 16 + hi16] = *reinterpret_cast<unsigned int*>(&hv);
}

// ---------------------------------------------------------------------------
// p2 (R11-validated): one 512-thread block per 128-node bucket; in-LDS
// counting sort (int atomics only) then 8-rows-per-instruction f16 gather,
// xor-reduce, shfl redistribution, fused epilogue.
// ---------------------------------------------------------------------------
__global__ __launch_bounds__(P2_T) void p2(const unsigned int* __restrict__ plist,
                                           const unsigned int* __restrict__ FeU,
                                           const unsigned int* __restrict__ boff,
                                           const float* __restrict__ X,
                                           const float* __restrict__ X0,
                                           const float* __restrict__ A2,
                                           const float* __restrict__ c2,
                                           const float* __restrict__ Ww,
                                           const float* __restrict__ bw,
                                           float* __restrict__ out) {
    __shared__ unsigned int sbuf[P2_CAP];      // 18,432 B (node-sorted entries)
    __shared__ unsigned int cnt[128];
    __shared__ unsigned int pos[128];
    __shared__ unsigned int cursor[128];
    __shared__ float As[D * D], Ws[D * D], c2s[D], bws[D];
    int t = threadIdx.x;
    for (int i = t; i < D * D; i += P2_T) { As[i] = A2[i]; Ws[i] = Ww[i]; }
    if (t < D) { c2s[t] = c2[t]; bws[t] = bw[t]; }
    if (t < 128) cnt[t] = 0;
    __syncthreads();

    int b = blockIdx.x;
    int base = b << BSH;
    int start = (int)boff[b];
    int n = (int)boff[b + 1] - start;

    // 1) histogram by local node id
    for (int i = t; i < n; i += P2_T)
        atomicAdd(&cnt[plist[start + i] & BMSK], 1u);
    __syncthreads();

    // 2) inclusive scan of cnt into pos (Hillis-Steele over 128)
    unsigned int v = (t < 128) ? cnt[t] : 0;
    if (t < 128) pos[t] = v;
    __syncthreads();
    for (int off = 1; off < 128; off <<= 1) {
        unsigned int u = 0;
        if (t < 128 && t >= off) u = pos[t - off];
        __syncthreads();
        if (t < 128) pos[t] += u;
        __syncthreads();
    }
    if (t < 128) cursor[t] = pos[t] - v;       // exclusive offset
    __syncthreads();

    // 3) scatter into sbuf sorted by node
    for (int i = t; i < n; i += P2_T) {
        unsigned int ent = plist[start + i];
        unsigned int p = atomicAdd(&cursor[ent & BMSK], 1u);
        sbuf[p] = ent;
    }
    __syncthreads();

    // 4+5) 16 half-waves x 8 nodes; 8-rows-per-instruction gather + epilogue
    int hw = t >> 5, lane = t & 31;
    int k8 = lane >> 2;                        // row slot 0..7
    int h4 = lane & 3;                         // 16B chunk 0..3
    for (int r = 0; r < 8; ++r) {
        int ln = r * 16 + hw;
        int node = base + ln;
        if (node >= N_NODES) continue;
        int deg = (int)cnt[ln];
        int st  = (int)pos[ln] - deg;

        unsigned int a0 = 0u, a1 = 0u, a2 = 0u, a3 = 0u;   // 8 f16 accum (set A)
        unsigned int a4 = 0u, a5 = 0u, a6 = 0u, a7 = 0u;   // set B
        for (int j0 = 0; j0 < deg; j0 += 16) {
            int iA = j0 + k8, iB = j0 + 8 + k8;
            bool vA = (iA < deg), vB = (iB < deg);
            unsigned int eA = vA ? (sbuf[st + iA] >> BSH) : 0u;
            unsigned int eB = vB ? (sbuf[st + iB] >> BSH) : 0u;
            uint4 wA = *(const uint4*)(FeU + eA * 16 + h4 * 4);
            uint4 wB = *(const uint4*)(FeU + eB * 16 + h4 * 4);
            if (!vA) { wA.x = 0u; wA.y = 0u; wA.z = 0u; wA.w = 0u; }
            if (!vB) { wB.x = 0u; wB.y = 0u; wB.z = 0u; wB.w = 0u; }
            a0 = pkadd(a0, wA.x); a1 = pkadd(a1, wA.y);
            a2 = pkadd(a2, wA.z); a3 = pkadd(a3, wA.w);
            a4 = pkadd(a4, wB.x); a5 = pkadd(a5, wB.y);
            a6 = pkadd(a6, wB.z); a7 = pkadd(a7, wB.w);
        }
        a0 = pkadd(a0, a4); a1 = pkadd(a1, a5);
        a2 = pkadd(a2, a6); a3 = pkadd(a3, a7);
        // reduce across row-slots (lanes differing in bits 2..4, same h4)
#pragma unroll
        for (int m = 4; m < 32; m <<= 1) {
            a0 = pkadd(a0, __shfl_xor(a0, m, 32));
            a1 = pkadd(a1, __shfl_xor(a1, m, 32));
            a2 = pkadd(a2, __shfl_xor(a2, m, 32));
            a3 = pkadd(a3, __shfl_xor(a3, m, 32));
        }
        // redistribute: lane j needs sf[j]; group h=j>>3 holds d in [8h,8h+8)
        unsigned int b0 = __shfl(a0, lane >> 3, 32);
        unsigned int b1 = __shfl(a1, lane >> 3, 32);
        unsigned int b2 = __shfl(a2, lane >> 3, 32);
        unsigned int b3 = __shfl(a3, lane >> 3, 32);
        unsigned int x01 = (lane & 2) ? b1 : b0;
        unsigned int x23 = (lane & 2) ? b3 : b2;
        unsigned int xx  = (lane & 4) ? x23 : x01;
        __half2 hh = *(__half2*)&xx;
        float sf = (lane & 1) ? __high2float(hh) : __low2float(hh);

        float x = X[node * D + lane];
        float s1 = c2s[lane];
#pragma unroll
        for (int kk = 0; kk < D; ++kk) s1 = fmaf(__shfl(x, kk, 32), As[kk * D + lane], s1);
        float tt = sf + X0[node * D + lane];
        float s2 = 0.f;
#pragma unroll
        for (int kk = 0; kk < D; ++kk) s2 = fmaf(__shfl(tt, kk, 32), Ws[kk * D + lane], s2);
        out[node * D + lane] = 0.5f * fmaf((float)deg, s1, s2) + bws[lane];
    }
}

// ---------------------------------------------------------------------------
extern "C" void kernel_launch(void* const* d_in, const int* in_sizes, int n_in,
                              void* d_out, int out_size, void* d_ws, size_t ws_size,
                              hipStream_t stream) {
    const float* X      = (const float*)d_in[0];
    const float* X0     = (const float*)d_in[1];
    const float* atts   = (const float*)d_in[2];
    const float* W1w    = (const float*)d_in[3];
    const float* W1b    = (const float*)d_in[4];
    const float* W2w    = (const float*)d_in[5];
    const float* W2b    = (const float*)d_in[6];
    const float* Ww     = (const float*)d_in[7];
    const float* Wb     = (const float*)d_in[8];
    const int*   vertex = (const int*)d_in[9];
    const int*   edges  = (const int*)d_in[10];
    float*       out    = (float*)d_out;

    char* ws = (char*)d_ws;
    unsigned int* FeU   = (unsigned int*)(ws);                 //  3,200,000 B
    unsigned int* plist = (unsigned int*)(ws + 3200000);       // 12,800,000 B
    unsigned int* XhU   = (unsigned int*)(ws + 16000000);      //  6,400,000 B
    int*          seg   = (int*)         (ws + 22400000);      //    200,004 B
    unsigned int* bcnt  = (unsigned int*)(ws + 22600256);      //      3,128 B
    unsigned int* boff  = (unsigned int*)(ws + 22604352);      //      3,132 B
    unsigned int* bcur  = (unsigned int*)(ws + 22608512);      //      3,128 B
    float*        M1    = (float*)       (ws + 22612992);      //      4,096 B
    float*        A2    = (float*)       (ws + 22617088);      //      4,096 B
    float*        c1    = (float*)       (ws + 22621184);      //        128 B
    float*        c2    = (float*)       (ws + 22621312);      //        128 B

    hipMemsetAsync(bcnt, 0, NB * sizeof(unsigned int), stream);

    kXh       <<<(N_NODES * 16 + 255) / 256, 256, 0, stream>>>(X, XhU);
    k0_weights<<<1, 1024, 0, stream>>>(W1w, W1b, W2w, W2b, Ww, M1, c1, A2, c2);
    k_seg     <<<(N_EDGES + 256) / 256, 256, 0, stream>>>(edges, seg);
    p1h       <<<1024, 256, 0, stream>>>(vertex, bcnt);
    kscan     <<<1, 1024, 0, stream>>>(bcnt, boff, bcur);
    p1        <<<P1_BLKS, P1_T, 0, stream>>>(vertex, edges, bcur, plist);
    k2_edge   <<<(N_EDGES + 3) / 4, 256, 0, stream>>>(XhU, atts, vertex, seg, M1, c1, FeU);
    p2        <<<NB, P2_T, 0, stream>>>(plist, FeU, boff, X, X0, A2, c2, Ww, Wb, out);
}